// Round 7
// baseline (206.332 us; speedup 1.0000x reference)
//
#include <hip/hip_runtime.h>
#include <hip/hip_cooperative_groups.h>

namespace cg = cooperative_groups;

constexpr int   ND_  = 16;
constexpr int   C_   = 512;
constexpr float EPS_ = 1e-5f;
constexpr int   RPC  = 512;   // rows per chunk (4 LDS row-groups x 128)
constexpr int   NBLK = 256;   // 1 block/CU, cooperative co-resident
constexpr int   NTHR = 512;

// Single fused cooperative kernel: phase1 per-chunk stats -> partials,
// grid.sync, phase2 reduce partials -> scale/shift, grid.sync,
// phase3 normalize. Eliminates 2 launch gaps + halves partial traffic
// (RPC 256->512: 16.8MB -> 8.4MB RW). Plain loads/stores in phase 3
// (R6: nontemporal hurt -8us; memory-side L3 handles reuse already).
__global__ __launch_bounds__(NTHR, 1) void k_fused(
    const float2* __restrict__ X2, const int* __restrict__ dd,
    const float* __restrict__ gamma, const float* __restrict__ beta,
    float* __restrict__ part_sum, float* __restrict__ part_sq,
    int* __restrict__ pcnt, float* __restrict__ scale,
    float* __restrict__ shift, float4* __restrict__ Y4, int N) {
  __shared__ float2 ssum[4][ND_][128];   // 64 KB
  __shared__ float2 ssq [4][ND_][128];   // 64 KB
  __shared__ int    sd[RPC];             // 2 KB
  __shared__ int    scnt[ND_];
  __shared__ float  fsum[16][32];        // phase-2 tree
  __shared__ float  fsq [16][32];
  __shared__ int    fcnt[16];

  const int tid  = threadIdx.x;
  const int g    = tid >> 7;        // row-group 0..3
  const int lane = tid & 127;       // channel lane (float2)
  const int bid  = blockIdx.x;
  const int bx   = bid & 1;         // channel half
  const int by   = bid >> 1;        // row chunk
  const int nchunk = (N + RPC - 1) / RPC;

  // ---------------- phase 1: per-chunk stats ----------------
  for (int i = tid; i < 4 * ND_ * 128; i += NTHR) {
    ((float2*)ssum)[i] = make_float2(0.f, 0.f);
    ((float2*)ssq )[i] = make_float2(0.f, 0.f);
  }
  if (tid < ND_) scnt[tid] = 0;
  __syncthreads();

  const int r0 = by * RPC;
  const int r1 = min(N, r0 + RPC);
  const int nr = r1 - r0;

  for (int i = tid; i < nr; i += NTHR) {
    const int v = dd[r0 + i];
    sd[i] = v;
    if (bx == 0) atomicAdd(&scnt[v], 1);
  }
  __syncthreads();

  const int jr0 = g * 128;
  const int jr1 = min(nr, jr0 + 128);
  const int ch2 = bx * 128 + lane;  // float2 column (row = 256 float2)
  #pragma unroll 8
  for (int j = jr0; j < jr1; ++j) {
    const int    dn = sd[j];        // wave-uniform
    const float2 v  = X2[(size_t)(r0 + j) * (C_ / 2) + ch2];
    float2 a = ssum[g][dn][lane];
    a.x += v.x; a.y += v.y;
    ssum[g][dn][lane] = a;
    float2 b = ssq[g][dn][lane];
    b.x = fmaf(v.x, v.x, b.x);
    b.y = fmaf(v.y, v.y, b.y);
    ssq[g][dn][lane] = b;
  }
  __syncthreads();

  // merge row-groups 1..3 into 0
  if (tid < 128) {
    #pragma unroll
    for (int dom = 0; dom < ND_; ++dom) {
      float2 a = ssum[0][dom][tid];
      float2 b = ssq [0][dom][tid];
      #pragma unroll
      for (int gg = 1; gg < 4; ++gg) {
        const float2 a1 = ssum[gg][dom][tid];
        const float2 b1 = ssq [gg][dom][tid];
        a.x += a1.x; a.y += a1.y;
        b.x += b1.x; b.y += b1.y;
      }
      ssum[0][dom][tid] = a;
      ssq [0][dom][tid] = b;
    }
  }
  __syncthreads();

  {
    float2* ps = (float2*)part_sum;
    float2* pq = (float2*)part_sq;
    const size_t base = (size_t)by * ND_ * (C_ / 2);
    for (int idx = tid; idx < ND_ * 128; idx += NTHR) {
      const int dom = idx >> 7;
      const int ln  = idx & 127;
      const size_t o = base + dom * (C_ / 2) + bx * 128 + ln;
      ps[o] = ssum[0][dom][ln];
      pq[o] = ssq [0][dom][ln];
    }
    if (bx == 0 && tid < ND_) pcnt[by * ND_ + tid] = scnt[tid];
  }

  __threadfence();
  cg::this_grid().sync();

  // ---------------- phase 2: partials -> scale/shift ----------------
  // 8192 outputs over 256 blocks = 32/block; 16 chunk-segments/output.
  {
    const int lane2 = tid & 31;
    const int seg   = tid >> 5;          // 0..15
    const int out0  = bid * 32;
    const int gid   = out0 + lane2;      // dom*512 + c
    const int dom   = out0 >> 9;
    const int c     = gid & (C_ - 1);
    const int cpl   = (nchunk + 15) / 16;

    float s = 0.f, q = 0.f;
    int   cn = 0;
    for (int k = 0; k < cpl; ++k) {
      const int ch = seg * cpl + k;
      if (ch < nchunk) {
        const size_t o = ((size_t)ch * ND_ + dom) * C_ + c;
        s += part_sum[o];
        q += part_sq[o];
        cn += pcnt[ch * ND_ + dom];
      }
    }
    fsum[seg][lane2] = s;
    fsq [seg][lane2] = q;
    if (lane2 == 0) fcnt[seg] = cn;
    __syncthreads();

    if (tid < 32) {
      float S = 0.f, Q = 0.f;
      int CN = 0;
      #pragma unroll
      for (int sg = 0; sg < 16; ++sg) {
        S += fsum[sg][tid];
        Q += fsq [sg][tid];
        CN += fcnt[sg];
      }
      const float fc   = fmaxf((float)CN, 1.f);
      const float mean = S / fc;
      const float var  = Q / fc - mean * mean;
      const float inv  = rsqrtf(var + EPS_);
      const int   gg   = out0 + tid;
      const float sc   = inv * gamma[gg];
      scale[gg] = sc;
      shift[gg] = fmaf(-mean, sc, beta[gg]);
    }
  }

  __threadfence();
  cg::this_grid().sync();

  // ---------------- phase 3: normalize ----------------
  {
    const float4* X4     = (const float4*)X2;
    const float4* scale4 = (const float4*)scale;
    const float4* shift4 = (const float4*)shift;
    const int total4 = N * (C_ / 4);
    const int stride = NBLK * NTHR;
    for (int i = bid * NTHR + tid; i < total4; i += stride) {
      const int n  = i >> 7;          // C/4 = 128 float4 per row
      const int c4 = i & 127;
      const int dn = dd[n];           // wave-uniform
      const float4 x  = X4[i];
      const float4 sc = scale4[dn * (C_ / 4) + c4];
      const float4 sh = shift4[dn * (C_ / 4) + c4];
      float4 y;
      y.x = fmaf(x.x, sc.x, sh.x);
      y.y = fmaf(x.y, sc.y, sh.y);
      y.z = fmaf(x.z, sc.z, sh.z);
      y.w = fmaf(x.w, sc.w, sh.w);
      Y4[i] = y;
    }
  }
}

extern "C" void kernel_launch(void* const* d_in, const int* in_sizes, int n_in,
                              void* d_out, int out_size, void* d_ws, size_t ws_size,
                              hipStream_t stream) {
  const float2* X2    = (const float2*)d_in[0];
  const int*    dd    = (const int*)  d_in[1];
  // d_in[2] = parameter_t, d_in[3] = fm_mean : unused by the reference math
  const float*  gamma = (const float*)d_in[4];
  const float*  beta  = (const float*)d_in[5];
  float*        out   = (float*)d_out;

  int N = in_sizes[1];                        // 65536
  const int NCHUNK = (N + RPC - 1) / RPC;     // 128

  // Partials in d_out head (consumed in phase 2, overwritten in phase 3):
  float* part_sum = out;
  float* part_sq  = out + (size_t)NCHUNK * ND_ * C_;
  int*   pcnt     = (int*)(part_sq + (size_t)NCHUNK * ND_ * C_);
  // scale/shift survive into phase 3 -> d_ws (64 KB).
  float* scale = (float*)d_ws;
  float* shift = scale + ND_ * C_;
  float4* Y4 = (float4*)out;

  void* args[] = {(void*)&X2, (void*)&dd, (void*)&gamma, (void*)&beta,
                  (void*)&part_sum, (void*)&part_sq, (void*)&pcnt,
                  (void*)&scale, (void*)&shift, (void*)&Y4, (void*)&N};
  hipLaunchCooperativeKernel((const void*)k_fused, dim3(NBLK), dim3(NTHR),
                             args, 0, stream);
}

// Round 8
// 78.285 us; speedup vs baseline: 2.6357x; 2.6357x over previous
//
#include <hip/hip_runtime.h>

constexpr int   ND_  = 16;
constexpr int   C_   = 512;
constexpr float EPS_ = 1e-5f;
constexpr int   RPC  = 512;   // rows per chunk (halves partial traffic vs R3)

// ---------------- Kernel 1: per-chunk partial stats -----------------------
// grid = (4, N/RPC) = (4,128) = 512 blocks; block = 256 thr = 4 row-groups
// x 64 float2-lanes. Block (bx, by): channel quarter [bx*128, +128) floats of
// rows [by*512, +512). Each row-group accumulates its own LDS set (no
// cross-wave RMW), merged across groups, dumped once -> NCHUNK=128 partials
// (16.8 MB RW vs R3's 33.5). 66 KB LDS -> 2 blocks/CU -> 8 waves/CU, same
// occupancy as R3. (R4 atomics, R6 nt-stores, R7 coop fusion all regressed.)
__global__ __launch_bounds__(256) void k_stats(
    const float2* __restrict__ X2, const int* __restrict__ dd,
    float* __restrict__ part_sum, float* __restrict__ part_sq,
    int* __restrict__ pcnt, int N) {
  __shared__ float2 ssum[4][ND_][64];   // 32 KB
  __shared__ float2 ssq [4][ND_][64];   // 32 KB
  __shared__ int    sd[RPC];            // 2 KB
  __shared__ int    scnt[ND_];

  const int tid  = threadIdx.x;
  const int g    = tid >> 6;        // row-group 0..3
  const int lane = tid & 63;        // float2 lane within quarter
  const int bx   = blockIdx.x;      // channel quarter 0..3
  const int by   = blockIdx.y;      // row chunk

  for (int i = tid; i < 4 * ND_ * 64; i += 256) {
    ((float2*)ssum)[i] = make_float2(0.f, 0.f);
    ((float2*)ssq )[i] = make_float2(0.f, 0.f);
  }
  if (tid < ND_) scnt[tid] = 0;
  __syncthreads();

  const int r0 = by * RPC;
  const int r1 = min(N, r0 + RPC);
  const int nr = r1 - r0;

  for (int i = tid; i < nr; i += 256) {
    const int v = dd[r0 + i];
    sd[i] = v;
    if (bx == 0) atomicAdd(&scnt[v], 1);
  }
  __syncthreads();

  const int jr0 = g * 128;          // 4 groups x 128 rows = 512
  const int jr1 = min(nr, jr0 + 128);
  const int ch2 = bx * 64 + lane;   // float2 column (row = 256 float2)
  #pragma unroll 8
  for (int j = jr0; j < jr1; ++j) {
    const int    dn = sd[j];        // wave-uniform
    const float2 v  = X2[(size_t)(r0 + j) * (C_ / 2) + ch2];
    float2 a = ssum[g][dn][lane];
    a.x += v.x; a.y += v.y;
    ssum[g][dn][lane] = a;
    float2 b = ssq[g][dn][lane];
    b.x = fmaf(v.x, v.x, b.x);
    b.y = fmaf(v.y, v.y, b.y);
    ssq[g][dn][lane] = b;
  }
  __syncthreads();

  // merge groups 1..3 into 0, parallel over all 256 threads (ND*64 = 1024)
  for (int idx = tid; idx < ND_ * 64; idx += 256) {
    const int dom = idx >> 6;
    const int ln  = idx & 63;
    float2 a = ssum[0][dom][ln];
    float2 b = ssq [0][dom][ln];
    #pragma unroll
    for (int gg = 1; gg < 4; ++gg) {
      const float2 a1 = ssum[gg][dom][ln];
      const float2 b1 = ssq [gg][dom][ln];
      a.x += a1.x; a.y += a1.y;
      b.x += b1.x; b.y += b1.y;
    }
    ssum[0][dom][ln] = a;
    ssq [0][dom][ln] = b;
  }
  __syncthreads();

  float2* ps = (float2*)part_sum;
  float2* pq = (float2*)part_sq;
  const size_t base = (size_t)by * ND_ * (C_ / 2);
  for (int idx = tid; idx < ND_ * 64; idx += 256) {
    const int dom = idx >> 6;
    const int ln  = idx & 63;
    const size_t o = base + dom * (C_ / 2) + bx * 64 + ln;
    ps[o] = ssum[0][dom][ln];
    pq[o] = ssq [0][dom][ln];
  }
  if (bx == 0 && tid < ND_) pcnt[by * ND_ + tid] = scnt[tid];
}

// ---------------- Kernel 2: reduce partials -> scale/shift ----------------
// grid = (ND_*C_)/32 = 256 blocks x 256 threads; block owns 32 outputs,
// 8 chunk-segments per output reduced via LDS. nchunk = 128.
__global__ __launch_bounds__(256) void k_finalize(
    const float* __restrict__ part_sum, const float* __restrict__ part_sq,
    const int* __restrict__ pcnt, const float* __restrict__ gamma,
    const float* __restrict__ beta, float* __restrict__ scale,
    float* __restrict__ shift, int nchunk) {
  __shared__ float ssum[8][32];
  __shared__ float ssq [8][32];
  __shared__ int   scnt[8];

  const int t     = threadIdx.x;
  const int lane  = t & 31;
  const int seg   = t >> 5;
  const int out0  = blockIdx.x * 32;
  const int gid   = out0 + lane;
  const int dom   = out0 >> 9;
  const int c     = gid & (C_ - 1);
  const int cpl   = (nchunk + 7) / 8;

  float s = 0.f, q = 0.f;
  int   cn = 0;
  for (int k = 0; k < cpl; ++k) {
    const int ch = seg * cpl + k;
    if (ch < nchunk) {
      const size_t o = ((size_t)ch * ND_ + dom) * C_ + c;
      s += part_sum[o];
      q += part_sq[o];
      cn += pcnt[ch * ND_ + dom];
    }
  }
  ssum[seg][lane] = s;
  ssq [seg][lane] = q;
  if (lane == 0) scnt[seg] = cn;
  __syncthreads();

  if (t < 32) {
    float S = 0.f, Q = 0.f;
    #pragma unroll
    for (int sg = 0; sg < 8; ++sg) { S += ssum[sg][t]; Q += ssq[sg][t]; }
    int CN = 0;
    #pragma unroll
    for (int sg = 0; sg < 8; ++sg) CN += scnt[sg];
    const float fc   = fmaxf((float)CN, 1.f);
    const float mean = S / fc;
    const float var  = Q / fc - mean * mean;
    const float inv  = rsqrtf(var + EPS_);
    const int   g    = out0 + t;
    const float sc   = inv * gamma[g];
    scale[g] = sc;
    shift[g] = fmaf(-mean, sc, beta[g]);
  }
}

// ---------------- Kernel 3: normalize ------------------------------------
// Grid-stride float4, plain loads/stores (nt hurt -8us in R6; memory-side
// L3 already serves the X re-read, confirmed by R7's FETCH_SIZE).
__global__ __launch_bounds__(256) void k_norm(
    const float4* __restrict__ X4, const int* __restrict__ dd,
    const float4* __restrict__ scale4, const float4* __restrict__ shift4,
    float4* __restrict__ Y4, int total4) {
  int i = blockIdx.x * 256 + threadIdx.x;
  const int stride = gridDim.x * 256;
  for (; i < total4; i += stride) {
    const int n  = i >> 7;          // C/4 = 128 float4 per row
    const int c4 = i & 127;
    const int dn = dd[n];           // wave-uniform (128 float4 per row)
    const float4 x  = X4[i];
    const float4 sc = scale4[dn * (C_ / 4) + c4];
    const float4 sh = shift4[dn * (C_ / 4) + c4];
    float4 y;
    y.x = fmaf(x.x, sc.x, sh.x);
    y.y = fmaf(x.y, sc.y, sh.y);
    y.z = fmaf(x.z, sc.z, sh.z);
    y.w = fmaf(x.w, sc.w, sh.w);
    Y4[i] = y;
  }
}

extern "C" void kernel_launch(void* const* d_in, const int* in_sizes, int n_in,
                              void* d_out, int out_size, void* d_ws, size_t ws_size,
                              hipStream_t stream) {
  const float* X     = (const float*)d_in[0];
  const int*   dd    = (const int*)  d_in[1];
  // d_in[2] = parameter_t, d_in[3] = fm_mean : unused by the reference math
  const float* gamma = (const float*)d_in[4];
  const float* beta  = (const float*)d_in[5];
  float*       out   = (float*)d_out;

  const int N      = in_sizes[1];             // 65536
  const int NCHUNK = (N + RPC - 1) / RPC;     // 128

  // Partials live in d_out (scratch until k_norm overwrites it):
  //   part_sum[NCHUNK][16][512], part_sq[NCHUNK][16][512], pcnt[NCHUNK][16]
  float* part_sum = out;
  float* part_sq  = out + (size_t)NCHUNK * ND_ * C_;
  int*   pcnt     = (int*)(part_sq + (size_t)NCHUNK * ND_ * C_);
  // scale/shift must survive k_norm -> keep in d_ws (64 KB).
  float* scale = (float*)d_ws;
  float* shift = scale + ND_ * C_;

  dim3 g1(4, NCHUNK);
  k_stats<<<g1, 256, 0, stream>>>((const float2*)X, dd, part_sum, part_sq,
                                  pcnt, N);
  k_finalize<<<(ND_ * C_) / 32, 256, 0, stream>>>(
      part_sum, part_sq, pcnt, gamma, beta, scale, shift, NCHUNK);

  const int total4 = N * (C_ / 4);
  int blocks = (total4 + 255) / 256;
  if (blocks > 2048) blocks = 2048;
  k_norm<<<blocks, 256, 0, stream>>>((const float4*)X, dd,
                                     (const float4*)scale,
                                     (const float4*)shift,
                                     (float4*)out, total4);
}